// Round 13
// baseline (124.710 us; speedup 1.0000x reference)
//
#include <hip/hip_runtime.h>
#include <hip/hip_bf16.h>
#include <stdint.h>

// Problem constants
#define BATCH 64
#define CH 3
#define HW 224
#define PP 7
#define GHW 32           // 32x32 patches
#define PD 147           // 7*7*3
#define DIM 1024
#define NTOK 65536       // 64 * 1024 tokens

typedef int   i32x4 __attribute__((ext_vector_type(4)));
typedef float f32x4v __attribute__((ext_vector_type(4)));
typedef float f32x2v __attribute__((ext_vector_type(2)));

#define LGKM0_BARRIER() do {                                        \
    asm volatile("s_waitcnt lgkmcnt(0)" ::: "memory");              \
    __builtin_amdgcn_sched_barrier(0);                              \
    __builtin_amdgcn_s_barrier();                                   \
    __builtin_amdgcn_sched_barrier(0);                              \
} while (0)

// ---------------- prelude 1: mean|W| partials + pe table, one launch ----------------
__global__ void prep1(const float* __restrict__ W, float* __restrict__ part,
                      float* __restrict__ pe2) {
    int tid = threadIdx.x;
    if (blockIdx.x < 147) {
        __shared__ float red[256];
        int base = blockIdx.x * 1024;             // 147 blocks * 1024 = 150528
        float s = fabsf(W[base + tid]) + fabsf(W[base + tid + 256]) +
                  fabsf(W[base + tid + 512]) + fabsf(W[base + tid + 768]);
        red[tid] = s;
        __syncthreads();
        for (int off = 128; off > 0; off >>= 1) {
            if (tid < off) red[tid] += red[tid + off];
            __syncthreads();
        }
        if (tid == 0) part[blockIdx.x] = red[0];
    } else {
        int id = (blockIdx.x - 147) * 256 + tid;  // < 16384 = 32*512
        int g = id >> 9, c = id & 511;
        int k = c & 255;
        float omega = exp2f(-13.287712379549449f * (float)k * (1.0f / 255.0f));
        float arg = (float)g * omega;
        pe2[id] = (c < 256) ? sinf(arg) : cosf(arg);
    }
}

// ---------------- ternary weight quant -> int8, MFMA fragment layout ----------------
// Wq layout: [c = k>>4 (12)][d(1024)][j = k&15] int8, k padded to 192. 192 KB total.
__global__ void wquant(const float* __restrict__ W, const float* __restrict__ part,
                       float* __restrict__ swbuf, signed char* __restrict__ Wq) {
    __shared__ float red[256];
    int tid = threadIdx.x;
    red[tid] = (tid < 147) ? part[tid] : 0.f;
    __syncthreads();
    for (int off = 128; off > 0; off >>= 1) {
        if (tid < off) red[tid] += red[tid + off];
        __syncthreads();
    }
    float m = fmaxf(red[0] * (1.0f / 150528.0f), 1e-5f);
    float sw = 1.0f / m;
    if (blockIdx.x == 0 && tid == 0) swbuf[0] = m;   // dequant scale for gemm

    int e = blockIdx.x * 256 + tid;               // < 196608 = 1024*192
    int d = e / 192, k = e % 192;
    float t = 0.f;
    if (k < 147) {
        t = rintf(W[d * 147 + k] * sw);
        t = fminf(fmaxf(t, -1.f), 1.f);
    }
    Wq[(((k >> 4) << 10) | d) * 16 + (k & 15)] = (signed char)(int)t;
}

// ---------------- fused patchify + LN1 + int8 quant + i8 GEMM + LN2 + posemb ----------
// r13: PERSISTENT 8-tile loop, NO vmcnt(0) drains in the loop.
//  - grid 512 x 8 tiles (XCD-chunked), 512 threads = 8 waves (wn 0..7), wave 16x128,
//    bounds(512,2) -> 256-reg budget (no spill; r11's failure mode eliminated).
//  - B (weights) are tile-invariant -> loaded ONCE into 24 i32x4 regs/thread (96 VGPR);
//    GEMM phase has ZERO memory ops.
//  - All barriers are raw s_barrier preceded by lgkmcnt(0) only (LDS visibility);
//    nt stores of tile t drain across tile t+1's entire compute. x-prefetch for t+1
//    is issued BEFORE tile t's stores, so the phase-0 wait never waits on stores.
//  - r8's proven numerics/layouts throughout (absmax 0.03125).
// LDS (48640 B, no aliasing):
//   xs   [0,     9408)  : x-stage [c(3)][p1(7)][112] f32
//   A8   [9408, 12736)  : quantized A int8 [row(16)][208]
//   stats[12736, 13760) : [wn(8)][token(16)] {sum,sq} f32
//   sxl  [13760, 13824) : per-token dequant scale f32
//   T    [13824, 48640) : 8 wave-private regions of 272 16B-units (16x17 stride)
__global__ __launch_bounds__(512, 2) void fused(
    const float* __restrict__ x, const float* __restrict__ g1,
    const float* __restrict__ b1, const signed char* __restrict__ Wq,
    const float* __restrict__ swbuf, const float* __restrict__ bproj,
    const float* __restrict__ g2, const float* __restrict__ b2,
    const float* __restrict__ pe2, float* __restrict__ out) {
    extern __shared__ char lds[];
    float*        xs    = (float*)lds;
    uint32_t*     A8w   = (uint32_t*)(lds + 9408);
    const i32x4*  A4    = (const i32x4*)(lds + 9408);
    f32x2v*       stats = (f32x2v*)(lds + 12736); // [wn(8)][token(16)] {sum,sq}
    float*        sxl   = (float*)(lds + 13760);
    f32x4v*       T     = (f32x4v*)(lds + 13824); // epilogue transpose buffer

    int tid = threadIdx.x;
    int wave = tid >> 6, lane = tid & 63;
    int wn = wave;                                // col slice [wn*128, wn*128+128)
    int l15 = lane & 15, lg = lane >> 4;
    int bcol = wn * 128 + l15;

    const i32x4*  Wq4 = (const i32x4*)Wq;
    const f32x4v* x4  = (const f32x4v*)x;
    f32x4v*       xs4 = (f32x4v*)xs;

    // ---- prologue: B fragments into registers (tile-invariant), once ----
    i32x4 breg[3][8];
#pragma unroll
    for (int kk = 0; kk < 3; kk++)
#pragma unroll
        for (int n = 0; n < 8; n++)
            breg[kk][n] = Wq4[(kk * 4 + lg) * 1024 + bcol + n * 16];

    float inv_sw = swbuf[0];

    int xcd = blockIdx.x & 7, local = blockIdx.x >> 3;   // 64 blocks per XCD
    int tbase = xcd * 512 + local * 8;            // 8 consecutive tiles (gh-major)

    // ---- prefetch x for tile 0 ----
    f32x4v xv[2];
    {
        int lt = tbase;
        int gh = lt >> 7, rem = lt & 127, b = rem >> 1, half = rem & 1;
        int base4 = b * 37632 + gh * 392 + half * 28;
#pragma unroll
        for (int it = 0; it < 2; it++) {
            int j = tid + it * 512;
            if (j < 588) {
                int c = j / 196, r2 = j - c * 196, p1 = r2 / 28, i4 = r2 - p1 * 28;
                xv[it] = x4[base4 + c * 12544 + p1 * 56 + i4];
            }
        }
    }

#pragma unroll 1
    for (int i = 0; i < 8; i++) {
        int lt = tbase + i;
        int gh = lt >> 7, rem = lt & 127, b = rem >> 1, half = rem & 1;
        int rowbase = b * 1024 + gh * 32 + half * 16;

        // ---- phase 0: ds_write prefetched x; then issue next tile's prefetch ----
#pragma unroll
        for (int it = 0; it < 2; it++) {
            int j = tid + it * 512;
            if (j < 588) xs4[j] = xv[it];
        }
        if (i < 7) {
            int ltn = tbase + i + 1;
            int ghn = ltn >> 7, remn = ltn & 127, bn = remn >> 1, hn = remn & 1;
            int b4n = bn * 37632 + ghn * 392 + hn * 28;
#pragma unroll
            for (int it = 0; it < 2; it++) {
                int j = tid + it * 512;
                if (j < 588) {
                    int c = j / 196, r2 = j - c * 196, p1 = r2 / 28, i4 = r2 - p1 * 28;
                    xv[it] = x4[b4n + c * 12544 + p1 * 56 + i4];
                }
            }
        }
        LGKM0_BARRIER();                          // BAR A: xs visible

        // ---- phase 1: LN1 + per-token absmax int8 fake-quant -> A8 (256 threads) ----
        if (tid < 256) {
            int r = tid >> 4, sub = tid & 15;     // token r (0..15), k = sub*12 + ii
            float vals[12];
            float sum = 0.f, sq = 0.f;
#pragma unroll
            for (int ii = 0; ii < 12; ii++) {
                int k = sub * 12 + ii;
                float val = 0.f;
                if (k < 147) {
                    int c = k % 3, pp = k / 3, p1 = pp / 7, p2 = pp % 7;
                    val = xs[c * 784 + p1 * 112 + r * 7 + p2];
                }
                vals[ii] = val;
                sum += val; sq += val * val;
            }
#pragma unroll
            for (int m = 1; m < 16; m <<= 1) {
                sum += __shfl_xor(sum, m);
                sq  += __shfl_xor(sq, m);
            }
            float mu = sum * (1.0f / 147.0f);
            float rstd1 = rsqrtf(sq * (1.0f / 147.0f) - mu * mu + 1e-5f);
            float amax = 0.f;
#pragma unroll
            for (int ii = 0; ii < 12; ii++) {
                int k = sub * 12 + ii;
                if (k < 147) {
                    float v = (vals[ii] - mu) * rstd1 * g1[k] + b1[k];
                    vals[ii] = v;
                    amax = fmaxf(amax, fabsf(v));
                }
            }
#pragma unroll
            for (int m = 1; m < 16; m <<= 1) amax = fmaxf(amax, __shfl_xor(amax, m));
            float mx = fmaxf(amax, 1e-5f);
            float sx = 127.0f / mx;
            uint32_t w0 = 0, w1 = 0, w2 = 0;
#pragma unroll
            for (int ii = 0; ii < 12; ii++) {
                int k = sub * 12 + ii;
                float qv = 0.f;
                if (k < 147) qv = fminf(fmaxf(rintf(vals[ii] * sx), -128.f), 127.f);
                uint32_t byte = (uint32_t)((int)qv & 0xFF);
                if (ii < 4)      w0 |= byte << (8 * ii);
                else if (ii < 8) w1 |= byte << (8 * (ii - 4));
                else             w2 |= byte << (8 * (ii - 8));
            }
            int wb = r * 52 + sub * 3;            // (r*208 + sub*12)/4
            A8w[wb] = w0; A8w[wb + 1] = w1; A8w[wb + 2] = w2;
            if (sub == 0) sxl[r] = mx * (1.0f / 127.0f);
        }
        LGKM0_BARRIER();                          // BAR B: A8/sxl visible

        // ---- phase 2: i8 GEMM, B from REGISTERS (zero memory ops except A ds_read) ----
        i32x4 acc[8];
#pragma unroll
        for (int n = 0; n < 8; n++) acc[n] = (i32x4)0;

#pragma unroll
        for (int kk = 0; kk < 3; kk++) {
            i32x4 a = A4[l15 * 13 + kk * 4 + lg]; // token = l15, k-chunk = lg
#pragma unroll
            for (int n = 0; n < 8; n++)           // D[dcol][token]: operands swapped
                acc[n] = __builtin_amdgcn_mfma_i32_16x16x64_i8(breg[kk][n], a, acc[n], 0, 0, 0);
        }

        // ---- phase 3a: dequant + bias, LN2 stats over 1024 cols ----
        int token = l15;
        float sc = sxl[token] * inv_sw;
        int colbase = wn * 128 + lg * 4;

        float s = 0.f, q = 0.f;
#pragma unroll
        for (int n = 0; n < 8; n++) {
            int col = colbase + n * 16;
            f32x4v bp = *(const f32x4v*)(bproj + col);
#pragma unroll
            for (int rr = 0; rr < 4; rr++) {
                float v = (float)acc[n][rr] * sc + bp[rr];
                acc[n][rr] = __float_as_int(v);   // bit-cast in place
                s += v; q += v * v;
            }
        }
        s += __shfl_xor(s, 16); s += __shfl_xor(s, 32);
        q += __shfl_xor(q, 16); q += __shfl_xor(q, 32);
        if (lg == 0) {
            f32x2v sv; sv[0] = s; sv[1] = q;
            stats[wn * 16 + token] = sv;          // [wn][token], b64, conflict-free
        }
        LGKM0_BARRIER();                          // BAR C: stats visible

        float st = 0.f, qt = 0.f;
#pragma unroll
        for (int w = 0; w < 8; w++) {
            f32x2v sv = stats[w * 16 + token];
            st += sv[0]; qt += sv[1];
        }
        float mean = st * (1.0f / 1024.0f);
        float rstd = rsqrtf(qt * (1.0f / 1024.0f) - mean * mean + 1e-5f);

        // ---- phase 3b: LN2 apply + posemb, wave-private LDS transpose, nt stores ----
        const float* perow = (wn < 4) ? (pe2 + (half * 16 + token) * 512)
                                      : (pe2 + gh * 512 - 512);
        int wbaseu = wave * 272;                  // 272 16B-units per wave region

#pragma unroll
        for (int p = 0; p < 2; p++) {
#pragma unroll
            for (int ni = 0; ni < 4; ni++) {
                int n = p * 4 + ni;
                int col = colbase + n * 16;
                f32x4v gg = *(const f32x4v*)(g2 + col);
                f32x4v bb = *(const f32x4v*)(b2 + col);
                f32x4v pv = *(const f32x4v*)(perow + col);
                f32x4v o;
#pragma unroll
                for (int rr = 0; rr < 4; rr++) {
                    float v = __int_as_float(acc[n][rr]);
                    o[rr] = (v - mean) * rstd * gg[rr] + bb[rr] + pv[rr];
                }
                T[wbaseu + l15 * 17 + ni * 4 + lg] = o;
            }
#pragma unroll
            for (int j = 0; j < 4; j++) {
                f32x4v v = T[wbaseu + (j * 4 + lg) * 17 + l15];
                int row = rowbase + j * 4 + lg;
                int col = wn * 128 + p * 64 + l15 * 4;
                __builtin_nontemporal_store(v, (f32x4v*)(out + (size_t)row * 1024 + col));
            }
        }
        // no drain: stores float across the next tile (raw barriers wait lgkm only)
    }
}

extern "C" void kernel_launch(void* const* d_in, const int* in_sizes, int n_in,
                              void* d_out, int out_size, void* d_ws, size_t ws_size,
                              hipStream_t stream) {
    const float* x     = (const float*)d_in[0];
    const float* ln1_g = (const float*)d_in[1];
    const float* ln1_b = (const float*)d_in[2];
    const float* W     = (const float*)d_in[3];
    const float* bproj = (const float*)d_in[4];
    const float* ln2_g = (const float*)d_in[5];
    const float* ln2_b = (const float*)d_in[6];
    float* out = (float*)d_out;

    // workspace layout
    char* ws = (char*)d_ws;
    float*       pe2   = (float*)ws;                           // 65,536 B
    signed char* Wq    = (signed char*)(ws + 65536u);          // 196,608 B
    float*       part  = (float*)(ws + 65536u + 196608u);      // 147 floats
    float*       swbuf = part + 160;

    prep1<<<211, 256, 0, stream>>>(W, part, pe2);
    wquant<<<768, 256, 0, stream>>>(W, part, swbuf, Wq);
    fused<<<512, 512, 48640, stream>>>(x, ln1_g, ln1_b, Wq, swbuf, bproj,
                                       ln2_g, ln2_b, pe2, out);
}

// Round 14
// 105.092 us; speedup vs baseline: 1.1867x; 1.1867x over previous
//
#include <hip/hip_runtime.h>
#include <hip/hip_bf16.h>
#include <stdint.h>

// Problem constants
#define BATCH 64
#define CH 3
#define HW 224
#define PP 7
#define GHW 32           // 32x32 patches
#define PD 147           // 7*7*3
#define DIM 1024
#define NTOK 65536       // 64 * 1024 tokens

typedef int   i32x4 __attribute__((ext_vector_type(4)));
typedef float f32x4v __attribute__((ext_vector_type(4)));
typedef float f32x2v __attribute__((ext_vector_type(2)));

#define LGKM0_BARRIER() do {                                        \
    asm volatile("s_waitcnt lgkmcnt(0)" ::: "memory");              \
    __builtin_amdgcn_sched_barrier(0);                              \
    __builtin_amdgcn_s_barrier();                                   \
    __builtin_amdgcn_sched_barrier(0);                              \
} while (0)

// ---------------- prelude 1: mean|W| partials + pe table, one launch ----------------
__global__ void prep1(const float* __restrict__ W, float* __restrict__ part,
                      float* __restrict__ pe2) {
    int tid = threadIdx.x;
    if (blockIdx.x < 147) {
        __shared__ float red[256];
        int base = blockIdx.x * 1024;             // 147 blocks * 1024 = 150528
        float s = fabsf(W[base + tid]) + fabsf(W[base + tid + 256]) +
                  fabsf(W[base + tid + 512]) + fabsf(W[base + tid + 768]);
        red[tid] = s;
        __syncthreads();
        for (int off = 128; off > 0; off >>= 1) {
            if (tid < off) red[tid] += red[tid + off];
            __syncthreads();
        }
        if (tid == 0) part[blockIdx.x] = red[0];
    } else {
        int id = (blockIdx.x - 147) * 256 + tid;  // < 16384 = 32*512
        int g = id >> 9, c = id & 511;
        int k = c & 255;
        float omega = exp2f(-13.287712379549449f * (float)k * (1.0f / 255.0f));
        float arg = (float)g * omega;
        pe2[id] = (c < 256) ? sinf(arg) : cosf(arg);
    }
}

// ---------------- ternary weight quant -> int8, MFMA fragment layout ----------------
// Wq layout: [c = k>>4 (12)][d(1024)][j = k&15] int8, k padded to 192. 192 KB total.
__global__ void wquant(const float* __restrict__ W, const float* __restrict__ part,
                       float* __restrict__ swbuf, signed char* __restrict__ Wq) {
    __shared__ float red[256];
    int tid = threadIdx.x;
    red[tid] = (tid < 147) ? part[tid] : 0.f;
    __syncthreads();
    for (int off = 128; off > 0; off >>= 1) {
        if (tid < off) red[tid] += red[tid + off];
        __syncthreads();
    }
    float m = fmaxf(red[0] * (1.0f / 150528.0f), 1e-5f);
    float sw = 1.0f / m;
    if (blockIdx.x == 0 && tid == 0) swbuf[0] = m;   // dequant scale for gemm

    int e = blockIdx.x * 256 + tid;               // < 196608 = 1024*192
    int d = e / 192, k = e % 192;
    float t = 0.f;
    if (k < 147) {
        t = rintf(W[d * 147 + k] * sw);
        t = fminf(fmaxf(t, -1.f), 1.f);
    }
    Wq[(((k >> 4) << 10) | d) * 16 + (k & 15)] = (signed char)(int)t;
}

// ---------------- fused patchify + LN1 + int8 quant + i8 GEMM + LN2 + posemb ----------
// r14: PERSISTENT 16-tile loop with a VMEM-LOAD-FREE body (the r13 fix).
//  - 256 blocks (1/CU), 512 threads = 8 waves, bounds(512,2) -> 256-reg budget.
//  - Hoisted once in prologue: W frags -> 24 i32x4 regs; g1/b1/bproj/g2 -> LDS;
//    b2+pe folded into pvA/pvB regs (pe x-row = half*16+token, half = tile PARITY ->
//    only 2 tile-invariant rows/thread; y-row = gh = const). Value-ternary select.
//  - In-loop vmem: next-tile x prefetch (issued BEFORE this tile's stores -> counted
//    vmcnt, never a drain) + 8 nt stores/thread (drain across next tile's compute).
//  - Raw lgkm-only barriers; NO vmcnt(0) anywhere in the loop.
// LDS (58112 B):
//   xs    [0,     9408)  : x-stage [c(3)][p1(7)][112] f32
//   A8    [9408, 12736)  : quantized A int8 [row(16)][208]
//   stats [12736, 13760) : [wn(8)][token(16)] {sum,sq} f32
//   sxl   [13760, 13824) : per-token dequant scale f32
//   T     [13824, 48640) : 8 wave-private regions of 272 16B-units (16x17 stride)
//   bprojS[48640, 52736) : 1024 f32
//   g2S   [52736, 56832) : 1024 f32
//   g1s   [56832, 57536) : 147 f32 (pad 176)
//   b1s   [57536, 58240) : 147 f32
__global__ __launch_bounds__(512, 2) void fused(
    const float* __restrict__ x, const float* __restrict__ g1,
    const float* __restrict__ b1, const signed char* __restrict__ Wq,
    const float* __restrict__ swbuf, const float* __restrict__ bproj,
    const float* __restrict__ g2, const float* __restrict__ b2,
    const float* __restrict__ pe2, float* __restrict__ out) {
    extern __shared__ char lds[];
    float*        xs     = (float*)lds;
    uint32_t*     A8w    = (uint32_t*)(lds + 9408);
    const i32x4*  A4     = (const i32x4*)(lds + 9408);
    f32x2v*       stats  = (f32x2v*)(lds + 12736);
    float*        sxl    = (float*)(lds + 13760);
    f32x4v*       T      = (f32x4v*)(lds + 13824);
    f32x4v*       bprojS = (f32x4v*)(lds + 48640);
    f32x4v*       g2S    = (f32x4v*)(lds + 52736);
    float*        g1s    = (float*)(lds + 56832);
    float*        b1s    = (float*)(lds + 57536);

    int tid = threadIdx.x;
    int wave = tid >> 6, lane = tid & 63;
    int wn = wave;                                // col slice [wn*128, wn*128+128)
    int l15 = lane & 15, lg = lane >> 4;
    int token = l15;
    int colbase = wn * 128 + lg * 4;
    int bcol = wn * 128 + l15;

    int xcd = blockIdx.x & 7, local = blockIdx.x >> 3;   // 32 blocks per XCD
    int tbase = xcd * 512 + local * 16;           // 16 consecutive tiles, gh constant
    int ghc = tbase >> 7;

    const i32x4*  Wq4 = (const i32x4*)Wq;
    const f32x4v* x4  = (const f32x4v*)x;
    f32x4v*       xs4 = (f32x4v*)xs;

    // ---- prologue (no stores outstanding; any waits here are harmless) ----
    if (tid < 256) {
        bprojS[tid] = ((const f32x4v*)bproj)[tid];
        g2S[tid]    = ((const f32x4v*)g2)[tid];
    }
    if (tid < 147) { g1s[tid] = g1[tid]; b1s[tid] = b1[tid]; }
    float inv_sw = swbuf[0];

    i32x4 breg[3][8];
#pragma unroll
    for (int kk = 0; kk < 3; kk++)
#pragma unroll
        for (int n = 0; n < 8; n++)
            breg[kk][n] = Wq4[(kk * 4 + lg) * 1024 + bcol + n * 16];

    f32x4v pvA[8], pvB[8];                        // b2 + pe, rows for half=0 / half=1
    if (wn < 4) {
#pragma unroll
        for (int n = 0; n < 8; n++) {
            int col = colbase + n * 16;           // < 512
            f32x4v b2v = *(const f32x4v*)(b2 + col);
            pvA[n] = *(const f32x4v*)(pe2 + token * 512 + col) + b2v;
            pvB[n] = *(const f32x4v*)(pe2 + (16 + token) * 512 + col) + b2v;
        }
    } else {
#pragma unroll
        for (int n = 0; n < 8; n++) {
            int col = colbase + n * 16;           // in [512, 1024)
            f32x4v b2v = *(const f32x4v*)(b2 + col);
            f32x4v pY = *(const f32x4v*)(pe2 + ghc * 512 + (col - 512));
            pvA[n] = pY + b2v; pvB[n] = pvA[n];
        }
    }

    // prefetch x for tile 0 (half = 0)
    f32x4v xv[2];
    {
        int b0 = (tbase & 127) >> 1;
        int base4 = b0 * 37632 + ghc * 392;
#pragma unroll
        for (int it = 0; it < 2; it++) {
            int j = tid + it * 512;
            if (j < 588) {
                int c = j / 196, r2 = j - c * 196, p1 = r2 / 28, i4 = r2 - p1 * 28;
                xv[it] = x4[base4 + c * 12544 + p1 * 56 + i4];
            }
        }
    }
    __syncthreads();                              // single full sync (prologue only)

    // ==================== persistent 16-tile loop ====================
#pragma unroll 1
    for (int i = 0; i < 16; i++) {
        int lt = tbase + i;
        int remt = lt & 127;
        int bi = remt >> 1, half = remt & 1;      // half == i & 1
        int rowbase = bi * 1024 + ghc * 32 + half * 16;

        // ---- phase 0: ds_write prefetched x; issue next tile's prefetch ----
#pragma unroll
        for (int it = 0; it < 2; it++) {
            int j = tid + it * 512;
            if (j < 588) xs4[j] = xv[it];
        }
        if (i < 15) {
            int remn = (lt + 1) & 127;
            int bn = remn >> 1, hn = remn & 1;
            int b4n = bn * 37632 + ghc * 392 + hn * 28;
#pragma unroll
            for (int it = 0; it < 2; it++) {
                int j = tid + it * 512;
                if (j < 588) {
                    int c = j / 196, r2 = j - c * 196, p1 = r2 / 28, i4 = r2 - p1 * 28;
                    xv[it] = x4[b4n + c * 12544 + p1 * 56 + i4];
                }
            }
        }
        LGKM0_BARRIER();                          // BAR A: xs visible

        // ---- phase 1: LN1 + per-token absmax int8 fake-quant -> A8 (LDS params) ----
        if (tid < 256) {
            int r = tid >> 4, sub = tid & 15;     // token r (0..15), k = sub*12 + ii
            float vals[12];
            float sum = 0.f, sq = 0.f;
#pragma unroll
            for (int ii = 0; ii < 12; ii++) {
                int k = sub * 12 + ii;
                float val = 0.f;
                if (k < 147) {
                    int c = k % 3, pp = k / 3, p1 = pp / 7, p2 = pp % 7;
                    val = xs[c * 784 + p1 * 112 + r * 7 + p2];
                }
                vals[ii] = val;
                sum += val; sq += val * val;
            }
#pragma unroll
            for (int m = 1; m < 16; m <<= 1) {
                sum += __shfl_xor(sum, m);
                sq  += __shfl_xor(sq, m);
            }
            float mu = sum * (1.0f / 147.0f);
            float rstd1 = rsqrtf(sq * (1.0f / 147.0f) - mu * mu + 1e-5f);
            float amax = 0.f;
#pragma unroll
            for (int ii = 0; ii < 12; ii++) {
                int k = sub * 12 + ii;
                if (k < 147) {
                    float v = (vals[ii] - mu) * rstd1 * g1s[k] + b1s[k];
                    vals[ii] = v;
                    amax = fmaxf(amax, fabsf(v));
                }
            }
#pragma unroll
            for (int m = 1; m < 16; m <<= 1) amax = fmaxf(amax, __shfl_xor(amax, m));
            float mx = fmaxf(amax, 1e-5f);
            float sx = 127.0f / mx;
            uint32_t w0 = 0, w1 = 0, w2 = 0;
#pragma unroll
            for (int ii = 0; ii < 12; ii++) {
                int k = sub * 12 + ii;
                float qv = 0.f;
                if (k < 147) qv = fminf(fmaxf(rintf(vals[ii] * sx), -128.f), 127.f);
                uint32_t byte = (uint32_t)((int)qv & 0xFF);
                if (ii < 4)      w0 |= byte << (8 * ii);
                else if (ii < 8) w1 |= byte << (8 * (ii - 4));
                else             w2 |= byte << (8 * (ii - 8));
            }
            int wb = r * 52 + sub * 3;            // (r*208 + sub*12)/4
            A8w[wb] = w0; A8w[wb + 1] = w1; A8w[wb + 2] = w2;
            if (sub == 0) sxl[r] = mx * (1.0f / 127.0f);
        }
        LGKM0_BARRIER();                          // BAR B: A8/sxl visible

        // ---- phase 2: i8 GEMM, B from registers (only LDS reads for A) ----
        i32x4 acc[8];
#pragma unroll
        for (int n = 0; n < 8; n++) acc[n] = (i32x4)0;
#pragma unroll
        for (int kk = 0; kk < 3; kk++) {
            i32x4 a = A4[l15 * 13 + kk * 4 + lg];
#pragma unroll
            for (int n = 0; n < 8; n++)
                acc[n] = __builtin_amdgcn_mfma_i32_16x16x64_i8(breg[kk][n], a, acc[n], 0, 0, 0);
        }

        // ---- phase 3a: dequant + bias (bproj from LDS), LN2 stats ----
        float sc = sxl[token] * inv_sw;
        float s = 0.f, q = 0.f;
#pragma unroll
        for (int n = 0; n < 8; n++) {
            f32x4v bp = bprojS[(colbase >> 2) + n * 4];
#pragma unroll
            for (int rr = 0; rr < 4; rr++) {
                float v = (float)acc[n][rr] * sc + bp[rr];
                acc[n][rr] = __float_as_int(v);
                s += v; q += v * v;
            }
        }
        s += __shfl_xor(s, 16); s += __shfl_xor(s, 32);
        q += __shfl_xor(q, 16); q += __shfl_xor(q, 32);
        if (lg == 0) {
            f32x2v sv; sv[0] = s; sv[1] = q;
            stats[wn * 16 + token] = sv;
        }
        LGKM0_BARRIER();                          // BAR C: stats visible

        float st = 0.f, qt = 0.f;
#pragma unroll
        for (int w = 0; w < 8; w++) {
            f32x2v sv = stats[w * 16 + token];
            st += sv[0]; qt += sv[1];
        }
        float mean = st * (1.0f / 1024.0f);
        float rstd = rsqrtf(qt * (1.0f / 1024.0f) - mean * mean + 1e-5f);

        // ---- phase 3b: LN2 apply (+folded b2+pe from regs), transpose, nt stores ----
        int wbaseu = wave * 272;
#pragma unroll
        for (int p = 0; p < 2; p++) {
#pragma unroll
            for (int ni = 0; ni < 4; ni++) {
                const int n = p * 4 + ni;
                f32x4v gg = g2S[(colbase >> 2) + n * 4];
                f32x4v pv = half ? pvB[n] : pvA[n];   // value select, compile-time n
                f32x4v o;
#pragma unroll
                for (int rr = 0; rr < 4; rr++) {
                    float v = __int_as_float(acc[n][rr]);
                    o[rr] = (v - mean) * rstd * gg[rr] + pv[rr];
                }
                T[wbaseu + l15 * 17 + ni * 4 + lg] = o;
            }
#pragma unroll
            for (int j = 0; j < 4; j++) {
                f32x4v v = T[wbaseu + (j * 4 + lg) * 17 + l15];
                int row = rowbase + j * 4 + lg;
                int col = wn * 128 + p * 64 + l15 * 4;
                __builtin_nontemporal_store(v, (f32x4v*)(out + (size_t)row * 1024 + col));
            }
        }
        // no drain: stores retire across the next tile's LDS/ALU phases
    }
}

extern "C" void kernel_launch(void* const* d_in, const int* in_sizes, int n_in,
                              void* d_out, int out_size, void* d_ws, size_t ws_size,
                              hipStream_t stream) {
    const float* x     = (const float*)d_in[0];
    const float* ln1_g = (const float*)d_in[1];
    const float* ln1_b = (const float*)d_in[2];
    const float* W     = (const float*)d_in[3];
    const float* bproj = (const float*)d_in[4];
    const float* ln2_g = (const float*)d_in[5];
    const float* ln2_b = (const float*)d_in[6];
    float* out = (float*)d_out;

    // workspace layout
    char* ws = (char*)d_ws;
    float*       pe2   = (float*)ws;                           // 65,536 B
    signed char* Wq    = (signed char*)(ws + 65536u);          // 196,608 B
    float*       part  = (float*)(ws + 65536u + 196608u);      // 147 floats
    float*       swbuf = part + 160;

    prep1<<<211, 256, 0, stream>>>(W, part, pe2);
    wquant<<<768, 256, 0, stream>>>(W, part, swbuf, Wq);
    fused<<<256, 512, 58240, stream>>>(x, ln1_g, ln1_b, Wq, swbuf, bproj,
                                       ln2_g, ln2_b, pe2, out);
}

// Round 15
// 100.096 us; speedup vs baseline: 1.2459x; 1.0499x over previous
//
#include <hip/hip_runtime.h>
#include <hip/hip_bf16.h>
#include <stdint.h>

// Problem constants
#define BATCH 64
#define CH 3
#define HW 224
#define PP 7
#define GHW 32           // 32x32 patches
#define PD 147           // 7*7*3
#define DIM 1024
#define NTOK 65536       // 64 * 1024 tokens

typedef int   i32x4 __attribute__((ext_vector_type(4)));
typedef float f32x4v __attribute__((ext_vector_type(4)));
typedef float f32x2v __attribute__((ext_vector_type(2)));

#define LGKM0_BARRIER() do {                                        \
    asm volatile("s_waitcnt lgkmcnt(0)" ::: "memory");              \
    __builtin_amdgcn_sched_barrier(0);                              \
    __builtin_amdgcn_s_barrier();                                   \
    __builtin_amdgcn_sched_barrier(0);                              \
} while (0)

// ---------------- prelude 1: mean|W| partials + pe table, one launch ----------------
__global__ void prep1(const float* __restrict__ W, float* __restrict__ part,
                      float* __restrict__ pe2) {
    int tid = threadIdx.x;
    if (blockIdx.x < 147) {
        __shared__ float red[256];
        int base = blockIdx.x * 1024;             // 147 blocks * 1024 = 150528
        float s = fabsf(W[base + tid]) + fabsf(W[base + tid + 256]) +
                  fabsf(W[base + tid + 512]) + fabsf(W[base + tid + 768]);
        red[tid] = s;
        __syncthreads();
        for (int off = 128; off > 0; off >>= 1) {
            if (tid < off) red[tid] += red[tid + off];
            __syncthreads();
        }
        if (tid == 0) part[blockIdx.x] = red[0];
    } else {
        int id = (blockIdx.x - 147) * 256 + tid;  // < 16384 = 32*512
        int g = id >> 9, c = id & 511;
        int k = c & 255;
        float omega = exp2f(-13.287712379549449f * (float)k * (1.0f / 255.0f));
        float arg = (float)g * omega;
        pe2[id] = (c < 256) ? sinf(arg) : cosf(arg);
    }
}

// ---------------- ternary weight quant -> int8, MFMA fragment layout ----------------
// Wq layout: [c = k>>4 (12)][d(1024)][j = k&15] int8, k padded to 192. 192 KB total.
__global__ void wquant(const float* __restrict__ W, const float* __restrict__ part,
                       float* __restrict__ swbuf, signed char* __restrict__ Wq) {
    __shared__ float red[256];
    int tid = threadIdx.x;
    red[tid] = (tid < 147) ? part[tid] : 0.f;
    __syncthreads();
    for (int off = 128; off > 0; off >>= 1) {
        if (tid < off) red[tid] += red[tid + off];
        __syncthreads();
    }
    float m = fmaxf(red[0] * (1.0f / 150528.0f), 1e-5f);
    float sw = 1.0f / m;
    if (blockIdx.x == 0 && tid == 0) swbuf[0] = m;   // dequant scale for gemm

    int e = blockIdx.x * 256 + tid;               // < 196608 = 1024*192
    int d = e / 192, k = e % 192;
    float t = 0.f;
    if (k < 147) {
        t = rintf(W[d * 147 + k] * sw);
        t = fminf(fmaxf(t, -1.f), 1.f);
    }
    Wq[(((k >> 4) << 10) | d) * 16 + (k & 15)] = (signed char)(int)t;
}

// ---------------- fused patchify + LN1 + int8 quant + i8 GEMM + LN2 + posemb ----------
// r15 = r14 + ONE change: the in-loop x prefetch is inline-asm global_load_dwordx4
// (invisible to the compiler's SIWaitcnt pass) and phase 0 opens with a hand-placed
// s_waitcnt vmcnt(8). Rationale: r14's compiler-visible xv load is consumed across
// the loop back-edge; the waitcnt pass merges conservatively at the loop header and
// emits vmcnt(0) there -> drains the 16-op store burst EVERY tile (~2.6 us x 16).
// With asm loads, the loop contains ZERO compiler vmcnt waits; per-wave issue order
// is [2 loads ... 8 stores] per tile and vmcnt retires in issue order, so vmcnt(8)
// at the next tile's top guarantees exactly the 2 loads -- never waits on stores.
// Everything else identical to r14 (absmax-proven numerics).
// LDS (58240 B): xs[0,9408) A8[9408,12736) stats[12736,13760) sxl[13760,13824)
//   T[13824,48640) bprojS[48640,52736) g2S[52736,56832) g1s[56832,57536) b1s[57536,58240)
__global__ __launch_bounds__(512, 2) void fused(
    const float* __restrict__ x, const float* __restrict__ g1,
    const float* __restrict__ b1, const signed char* __restrict__ Wq,
    const float* __restrict__ swbuf, const float* __restrict__ bproj,
    const float* __restrict__ g2, const float* __restrict__ b2,
    const float* __restrict__ pe2, float* __restrict__ out) {
    extern __shared__ char lds[];
    float*        xs     = (float*)lds;
    uint32_t*     A8w    = (uint32_t*)(lds + 9408);
    const i32x4*  A4     = (const i32x4*)(lds + 9408);
    f32x2v*       stats  = (f32x2v*)(lds + 12736);
    float*        sxl    = (float*)(lds + 13760);
    f32x4v*       T      = (f32x4v*)(lds + 13824);
    f32x4v*       bprojS = (f32x4v*)(lds + 48640);
    f32x4v*       g2S    = (f32x4v*)(lds + 52736);
    float*        g1s    = (float*)(lds + 56832);
    float*        b1s    = (float*)(lds + 57536);

    int tid = threadIdx.x;
    int wave = tid >> 6, lane = tid & 63;
    int wn = wave;                                // col slice [wn*128, wn*128+128)
    int l15 = lane & 15, lg = lane >> 4;
    int token = l15;
    int colbase = wn * 128 + lg * 4;
    int bcol = wn * 128 + l15;

    int xcd = blockIdx.x & 7, local = blockIdx.x >> 3;   // 32 blocks per XCD
    int tbase = xcd * 512 + local * 16;           // 16 consecutive tiles, gh constant
    int ghc = tbase >> 7;

    const i32x4*  Wq4 = (const i32x4*)Wq;
    const f32x4v* x4  = (const f32x4v*)x;
    f32x4v*       xs4 = (f32x4v*)xs;

    // per-thread clamped x-stage decomposition (uniform 2 loads/thread/tile)
    int j0 = tid;                                 // < 512 (< 588 always)
    int j1 = tid + 512;
    int jc1 = (j1 < 588) ? j1 : 587;              // clamp: dup loads, never consumed
    int c0 = j0 / 196, r20 = j0 - c0 * 196, p10 = r20 / 28, i40 = r20 - p10 * 28;
    int c1 = jc1 / 196, r21 = jc1 - c1 * 196, p11 = r21 / 28, i41 = r21 - p11 * 28;
    int xoff0 = c0 * 12544 + p10 * 56 + i40;      // + base4 -> float4 index
    int xoff1 = c1 * 12544 + p11 * 56 + i41;

    // ---- prologue (no stores outstanding; compiler waits here are harmless) ----
    if (tid < 256) {
        bprojS[tid] = ((const f32x4v*)bproj)[tid];
        g2S[tid]    = ((const f32x4v*)g2)[tid];
    }
    if (tid < 147) { g1s[tid] = g1[tid]; b1s[tid] = b1[tid]; }
    float inv_sw = swbuf[0];

    i32x4 breg[3][8];
#pragma unroll
    for (int kk = 0; kk < 3; kk++)
#pragma unroll
        for (int n = 0; n < 8; n++)
            breg[kk][n] = Wq4[(kk * 4 + lg) * 1024 + bcol + n * 16];

    f32x4v pvA[8], pvB[8];                        // b2 + pe, rows for half=0 / half=1
    if (wn < 4) {
#pragma unroll
        for (int n = 0; n < 8; n++) {
            int col = colbase + n * 16;           // < 512
            f32x4v b2v = *(const f32x4v*)(b2 + col);
            pvA[n] = *(const f32x4v*)(pe2 + token * 512 + col) + b2v;
            pvB[n] = *(const f32x4v*)(pe2 + (16 + token) * 512 + col) + b2v;
        }
    } else {
#pragma unroll
        for (int n = 0; n < 8; n++) {
            int col = colbase + n * 16;           // in [512, 1024)
            f32x4v b2v = *(const f32x4v*)(b2 + col);
            f32x4v pY = *(const f32x4v*)(pe2 + ghc * 512 + (col - 512));
            pvA[n] = pY + b2v; pvB[n] = pvA[n];
        }
    }

    // prefetch x for tile 0 (compiler loads; drained by the prologue syncthreads)
    f32x4v xv0, xv1;
    {
        int b0 = (tbase & 127) >> 1;
        int base4 = b0 * 37632 + ghc * 392;       // half = 0 at tile 0
        xv0 = x4[base4 + xoff0];
        xv1 = x4[base4 + xoff1];
    }
    __syncthreads();                              // single full drain (prologue only)

    // ==================== persistent 16-tile loop ====================
#pragma unroll 1
    for (int i = 0; i < 16; i++) {
        int lt = tbase + i;
        int remt = lt & 127;
        int bi = remt >> 1, half = remt & 1;      // half == i & 1
        int rowbase = bi * 1024 + ghc * 32 + half * 16;

        // ---- phase 0: counted wait (covers ONLY the 2 asm loads), ds_write, then
        //      issue next tile's asm prefetch ----
        asm volatile("s_waitcnt vmcnt(8)" ::: "memory");
        __builtin_amdgcn_sched_barrier(0);
        xs4[j0] = xv0;
        if (j1 < 588) xs4[j1] = xv1;
        {
            int remn = (lt + 1) & 127;
            int bn = remn >> 1, hn = remn & 1;
            int b4n = bn * 37632 + ghc * 392 + hn * 28;
            const f32x4v* a0 = x4 + b4n + xoff0;
            const f32x4v* a1 = x4 + b4n + xoff1;
            asm volatile("global_load_dwordx4 %0, %2, off\n\t"
                         "global_load_dwordx4 %1, %3, off"
                         : "=v"(xv0), "=v"(xv1)
                         : "v"(a0), "v"(a1)
                         : "memory");
        }
        LGKM0_BARRIER();                          // BAR A: xs visible (lgkm only)

        // ---- phase 1: LN1 + per-token absmax int8 fake-quant -> A8 (LDS params) ----
        if (tid < 256) {
            int r = tid >> 4, sub = tid & 15;     // token r (0..15), k = sub*12 + ii
            float vals[12];
            float sum = 0.f, sq = 0.f;
#pragma unroll
            for (int ii = 0; ii < 12; ii++) {
                int k = sub * 12 + ii;
                float val = 0.f;
                if (k < 147) {
                    int c = k % 3, pp = k / 3, p1 = pp / 7, p2 = pp % 7;
                    val = xs[c * 784 + p1 * 112 + r * 7 + p2];
                }
                vals[ii] = val;
                sum += val; sq += val * val;
            }
#pragma unroll
            for (int m = 1; m < 16; m <<= 1) {
                sum += __shfl_xor(sum, m);
                sq  += __shfl_xor(sq, m);
            }
            float mu = sum * (1.0f / 147.0f);
            float rstd1 = rsqrtf(sq * (1.0f / 147.0f) - mu * mu + 1e-5f);
            float amax = 0.f;
#pragma unroll
            for (int ii = 0; ii < 12; ii++) {
                int k = sub * 12 + ii;
                if (k < 147) {
                    float v = (vals[ii] - mu) * rstd1 * g1s[k] + b1s[k];
                    vals[ii] = v;
                    amax = fmaxf(amax, fabsf(v));
                }
            }
#pragma unroll
            for (int m = 1; m < 16; m <<= 1) amax = fmaxf(amax, __shfl_xor(amax, m));
            float mx = fmaxf(amax, 1e-5f);
            float sx = 127.0f / mx;
            uint32_t w0 = 0, w1 = 0, w2 = 0;
#pragma unroll
            for (int ii = 0; ii < 12; ii++) {
                int k = sub * 12 + ii;
                float qv = 0.f;
                if (k < 147) qv = fminf(fmaxf(rintf(vals[ii] * sx), -128.f), 127.f);
                uint32_t byte = (uint32_t)((int)qv & 0xFF);
                if (ii < 4)      w0 |= byte << (8 * ii);
                else if (ii < 8) w1 |= byte << (8 * (ii - 4));
                else             w2 |= byte << (8 * (ii - 8));
            }
            int wb = r * 52 + sub * 3;            // (r*208 + sub*12)/4
            A8w[wb] = w0; A8w[wb + 1] = w1; A8w[wb + 2] = w2;
            if (sub == 0) sxl[r] = mx * (1.0f / 127.0f);
        }
        LGKM0_BARRIER();                          // BAR B: A8/sxl visible

        // ---- phase 2: i8 GEMM, B from registers (only LDS reads for A) ----
        i32x4 acc[8];
#pragma unroll
        for (int n = 0; n < 8; n++) acc[n] = (i32x4)0;
#pragma unroll
        for (int kk = 0; kk < 3; kk++) {
            i32x4 a = A4[l15 * 13 + kk * 4 + lg];
#pragma unroll
            for (int n = 0; n < 8; n++)
                acc[n] = __builtin_amdgcn_mfma_i32_16x16x64_i8(breg[kk][n], a, acc[n], 0, 0, 0);
        }

        // ---- phase 3a: dequant + bias (bproj from LDS), LN2 stats ----
        float sc = sxl[token] * inv_sw;
        float s = 0.f, q = 0.f;
#pragma unroll
        for (int n = 0; n < 8; n++) {
            f32x4v bp = bprojS[(colbase >> 2) + n * 4];
#pragma unroll
            for (int rr = 0; rr < 4; rr++) {
                float v = (float)acc[n][rr] * sc + bp[rr];
                acc[n][rr] = __float_as_int(v);
                s += v; q += v * v;
            }
        }
        s += __shfl_xor(s, 16); s += __shfl_xor(s, 32);
        q += __shfl_xor(q, 16); q += __shfl_xor(q, 32);
        if (lg == 0) {
            f32x2v sv; sv[0] = s; sv[1] = q;
            stats[wn * 16 + token] = sv;
        }
        LGKM0_BARRIER();                          // BAR C: stats visible

        float st = 0.f, qt = 0.f;
#pragma unroll
        for (int w = 0; w < 8; w++) {
            f32x2v sv = stats[w * 16 + token];
            st += sv[0]; qt += sv[1];
        }
        float mean = st * (1.0f / 1024.0f);
        float rstd = rsqrtf(qt * (1.0f / 1024.0f) - mean * mean + 1e-5f);

        // ---- phase 3b: LN2 apply (+folded b2+pe from regs), transpose, nt stores ----
        int wbaseu = wave * 272;
#pragma unroll
        for (int p = 0; p < 2; p++) {
#pragma unroll
            for (int ni = 0; ni < 4; ni++) {
                const int n = p * 4 + ni;
                f32x4v gg = g2S[(colbase >> 2) + n * 4];
                f32x4v pv = half ? pvB[n] : pvA[n];   // value select, compile-time n
                f32x4v o;
#pragma unroll
                for (int rr = 0; rr < 4; rr++) {
                    float v = __int_as_float(acc[n][rr]);
                    o[rr] = (v - mean) * rstd * gg[rr] + pv[rr];
                }
                T[wbaseu + l15 * 17 + ni * 4 + lg] = o;
            }
#pragma unroll
            for (int j = 0; j < 4; j++) {
                f32x4v v = T[wbaseu + (j * 4 + lg) * 17 + l15];
                int row = rowbase + j * 4 + lg;
                int col = wn * 128 + p * 64 + l15 * 4;
                __builtin_nontemporal_store(v, (f32x4v*)(out + (size_t)row * 1024 + col));
            }
        }
        // no drain: the 8 stores retire across the next tile's LDS/ALU phases
    }
}

extern "C" void kernel_launch(void* const* d_in, const int* in_sizes, int n_in,
                              void* d_out, int out_size, void* d_ws, size_t ws_size,
                              hipStream_t stream) {
    const float* x     = (const float*)d_in[0];
    const float* ln1_g = (const float*)d_in[1];
    const float* ln1_b = (const float*)d_in[2];
    const float* W     = (const float*)d_in[3];
    const float* bproj = (const float*)d_in[4];
    const float* ln2_g = (const float*)d_in[5];
    const float* ln2_b = (const float*)d_in[6];
    float* out = (float*)d_out;

    // workspace layout
    char* ws = (char*)d_ws;
    float*       pe2   = (float*)ws;                           // 65,536 B
    signed char* Wq    = (signed char*)(ws + 65536u);          // 196,608 B
    float*       part  = (float*)(ws + 65536u + 196608u);      // 147 floats
    float*       swbuf = part + 160;

    prep1<<<211, 256, 0, stream>>>(W, part, pe2);
    wquant<<<768, 256, 0, stream>>>(W, part, swbuf, Wq);
    fused<<<256, 512, 58240, stream>>>(x, ln1_g, ln1_b, Wq, swbuf, bproj,
                                       ln2_g, ln2_b, pe2, out);
}